// Round 4
// baseline (113.270 us; speedup 1.0000x reference)
//
#include <hip/hip_runtime.h>
#include <hip/hip_bf16.h>
#include <math.h>

// ---------------------------------------------------------------------------
// Metric loss (lifted structure) on MI355X.
// R4: atomic-free egemm (per-block partial row/col sums -> plain stores ->
// separate rowreduce kernel) + double-buffered K-loop (stage(next) ->
// compute(cur) -> barrier, so the vmcnt drain overlaps MFMA).
// Single triangular Gram over 6144 unique rows (text 4096 + shape 2048),
// diag-free partial sums St (text cols) / Ss (shape cols):
//   tt:  ns = St[2p]+St[2p+1] - 2*exp(1-Dp)
//   st:  ns = G(u1)+G(u2) + e - 2*exp(1-Dp),  G = St + 2*Ss
// ---------------------------------------------------------------------------

typedef __bf16 bf16x8 __attribute__((ext_vector_type(8)));
typedef float floatx4 __attribute__((ext_vector_type(4)));

#define KD 256
#define NU 6144
#define NBU 48
#define TU (NBU * (NBU + 1) / 2) /* 1176 */
#define BM 128
#define BK 32
#define ECONST 2.718281828459045f
#define LOSS_BLOCKS 1536

// logical (row r, 16B k-slot q) -> bf16 element index in swizzled LDS tile
#define LSLOT(r, q) ((((r) * 4 + ((q) ^ (((r) >> 1) & 3)))) * 8)

__device__ __forceinline__ void gload_lds16(const void* g, void* l) {
  __builtin_amdgcn_global_load_lds((const __attribute__((address_space(1))) unsigned int*)g,
                                   (__attribute__((address_space(3))) unsigned int*)l,
                                   16, 0, 0);
}

// ---- prep: bf16 convert unique rows, row sq from bf16 ----------------------
__global__ __launch_bounds__(256) void prep_kernel(const float* __restrict__ text,
                                                   const float* __restrict__ shape,
                                                   __bf16* __restrict__ Xu,
                                                   float* __restrict__ sq) {
  int gt = blockIdx.x * 256 + threadIdx.x;
  int wave = gt >> 6;  // one wave per unique row, 0..6143
  int lane = gt & 63;
  const float* src = (wave < 4096) ? (text + (size_t)wave * KD)
                                   : (shape + (size_t)(wave - 4096) * KD);
  __bf16* dst = Xu + (size_t)wave * KD;
  float s = 0.f;
#pragma unroll
  for (int j = 0; j < 4; ++j) {
    int idx = j * 64 + lane;
    float f = src[idx];
    __bf16 h = (__bf16)f;  // RNE
    dst[idx] = h;
    float fv = (float)h;   // square the ROUNDED value (consistency with MFMA G)
    s += fv * fv;
  }
#pragma unroll
  for (int m = 1; m < 64; m <<= 1) s += __shfl_xor(s, m, 64);
  if (lane == 0) sq[wave] = s;
}

// ---- triangular Gram + E + per-block partial row/col sums (no atomics) -----
__global__ __launch_bounds__(256, 4) void egemm_tri_kernel(
    const __bf16* __restrict__ X, const float* __restrict__ sq,
    float* __restrict__ rowpart, float* __restrict__ colpart) {
  __shared__ __align__(16) __bf16 As[2][BM * BK];
  __shared__ __align__(16) __bf16 Bs[2][BM * BK];
  __shared__ float rowbuf[2][128];
  __shared__ float colbuf[2][128];

  // triangular decode: by >= bx
  const int t = blockIdx.x;
  int by = (int)((sqrtf(8.0f * (float)t + 1.0f) - 1.0f) * 0.5f);
  while ((by + 1) * (by + 2) / 2 <= t) ++by;
  while (by * (by + 1) / 2 > t) --by;
  const int bx = t - by * (by + 1) / 2;

  const int mBase = by * BM;  // rows (mBase >= nBase)
  const int nBase = bx * BM;  // cols
  const bool diag = (by == bx);

  const int tid = threadIdx.x;
  const int lane = tid & 63;
  const int w = tid >> 6;  // 2x2 wave grid of 64x64 tiles
  const int warpM = w >> 1, warpN = w & 1;
  const int quad = lane >> 4;
  const int l15 = lane & 15;

  floatx4 acc[4][4] = {};

  // staging: chunk c (16 rows, 1KB); lane L -> row 16c+(L>>2), swizzled k-slot
  const int sRow = lane >> 2;
  const int sCol = (((lane & 3) ^ ((lane >> 3) & 3))) * 8;

#define STAGE(buf, kt)                                                                     \
  {                                                                                        \
    _Pragma("unroll") for (int h = 0; h < 2; ++h) {                                        \
      int c = h * 4 + w;                                                                   \
      gload_lds16(X + (size_t)(mBase + c * 16 + sRow) * KD + (kt) + sCol, &As[buf][c * 512]); \
      gload_lds16(X + (size_t)(nBase + c * 16 + sRow) * KD + (kt) + sCol, &Bs[buf][c * 512]); \
    }                                                                                      \
  }

  STAGE(0, 0);
  __syncthreads();
#pragma unroll
  for (int i = 0; i < KD / BK; ++i) {
    const int cur = i & 1;
    if (i < KD / BK - 1) STAGE(cur ^ 1, (i + 1) * BK);  // async into other buffer

    bf16x8 af[4], bfr[4];
#pragma unroll
    for (int tm = 0; tm < 4; ++tm)
      af[tm] = *(const bf16x8*)&As[cur][LSLOT(warpM * 64 + tm * 16 + l15, quad)];
#pragma unroll
    for (int tn = 0; tn < 4; ++tn)
      bfr[tn] = *(const bf16x8*)&Bs[cur][LSLOT(warpN * 64 + tn * 16 + l15, quad)];
#pragma unroll
    for (int tm = 0; tm < 4; ++tm)
#pragma unroll
      for (int tn = 0; tn < 4; ++tn)
        acc[tm][tn] = __builtin_amdgcn_mfma_f32_16x16x32_bf16(af[tm], bfr[tn], acc[tm][tn], 0, 0, 0);
    __syncthreads();  // vmcnt drain lands AFTER the MFMA burst (overlap)
  }

  // ---- epilogue: E = exp(1-D), diag-free row+col sums ----
  const int rbase = mBase + warpM * 64;
  const int cbase = nBase + warpN * 64;
  float sqr[4][4], sqc[4];
#pragma unroll
  for (int tm = 0; tm < 4; ++tm)
#pragma unroll
    for (int r = 0; r < 4; ++r)
      sqr[tm][r] = sq[rbase + tm * 16 + quad * 4 + r];
#pragma unroll
  for (int tn = 0; tn < 4; ++tn)
    sqc[tn] = sq[cbase + tn * 16 + l15];

  const float L2E = 1.44269504088896f;
  float cs[4] = {0.f, 0.f, 0.f, 0.f};
#pragma unroll
  for (int tm = 0; tm < 4; ++tm) {
    float rs[4] = {0.f, 0.f, 0.f, 0.f};
#pragma unroll
    for (int tn = 0; tn < 4; ++tn) {
#pragma unroll
      for (int r = 0; r < 4; ++r) {
        float v = acc[tm][tn][r];
        float dsq = fmaf(-2.0f, v, sqr[tm][r] + sqc[tn]);
        float dst = sqrtf(fmaxf(dsq, 0.f));
        float ev = __builtin_amdgcn_exp2f(fmaf(-L2E, dst, L2E));
        // unique-level diagonal excluded (handled analytically downstream)
        if (diag && tm == tn && (quad * 4 + r) == l15) ev = 0.f;
        rs[r] += ev;
        cs[tn] += ev;
      }
    }
#pragma unroll
    for (int r = 0; r < 4; ++r) {
      float v = rs[r];
      v += __shfl_xor(v, 1, 64);
      v += __shfl_xor(v, 2, 64);
      v += __shfl_xor(v, 4, 64);
      v += __shfl_xor(v, 8, 64);
      if (l15 == 0) rowbuf[warpN][warpM * 64 + tm * 16 + quad * 4 + r] = v;
    }
  }
#pragma unroll
  for (int tn = 0; tn < 4; ++tn) {
    float v = cs[tn];
    v += __shfl_xor(v, 16, 64);
    v += __shfl_xor(v, 32, 64);
    if (quad == 0) colbuf[warpM][warpN * 64 + tn * 16 + l15] = v;
  }
  __syncthreads();

  if (tid < 128) {
    rowpart[(size_t)t * 128 + tid] = rowbuf[0][tid] + rowbuf[1][tid];
  } else {
    int c = tid - 128;
    colpart[(size_t)t * 128 + c] = diag ? 0.f : (colbuf[0][c] + colbuf[1][c]);
  }
}

// ---- gather per-block partials -> St / Ss (plain stores) -------------------
__global__ __launch_bounds__(256) void rowreduce_kernel(const float* __restrict__ rowpart,
                                                        const float* __restrict__ colpart,
                                                        float* __restrict__ rowacc) {
  // 24 blocks x 256 threads; stripe s = 2*blockIdx.x + (tid>>7), row r = tid&127
  const int s = blockIdx.x * 2 + (threadIdx.x >> 7);
  const int r = threadIdx.x & 127;
  float stv = 0.f, ssv = 0.f;
  const int base = s * (s + 1) / 2;
  // row contributions from blocks (by=s, bx=0..s): cols text iff bx<32
  for (int bx = 0; bx <= s; ++bx) {
    float v = rowpart[(size_t)(base + bx) * 128 + r];
    if (bx < 32) stv += v; else ssv += v;
  }
  // col contributions from blocks (by=s+1..47, bx=s): rows text iff by<32
  for (int by = s + 1; by < NBU; ++by) {
    float v = colpart[(size_t)(by * (by + 1) / 2 + s) * 128 + r];
    if (by < 32) stv += v; else ssv += v;
  }
  rowacc[s * 128 + r] = stv;        // St
  rowacc[NU + s * 128 + r] = ssv;   // Ss
}

// ---- per-pair fp32 distance + analytic ns + J; block partials --------------
__global__ __launch_bounds__(256) void loss_kernel(const float* __restrict__ text,
                                                   const float* __restrict__ shape,
                                                   const float* __restrict__ rowacc,
                                                   float* __restrict__ partials) {
  __shared__ float part[4];
  const float* St = rowacc;
  const float* Ss = rowacc + NU;
  int wv = blockIdx.x * 4 + (threadIdx.x >> 6);  // one wave per pair, 0..6143
  int lane = threadIdx.x & 63;
  const float *a, *b;
  float base, scale;
  if (wv < 2048) {  // tt pair p
    int p = wv;
    a = text + (size_t)(2 * p) * KD;
    b = text + (size_t)(2 * p + 1) * KD;
    base = St[2 * p] + St[2 * p + 1];
    scale = 1.0f / 4096.0f;
  } else {  // st pair
    int p = wv - 2048;
    int u1, u2;
    if (p < 2048) {  // (text_2p, shape_p)
      u1 = 2 * p; u2 = 4096 + p;
      a = text + (size_t)(2 * p) * KD;
      b = shape + (size_t)p * KD;
    } else {         // (shape_s, text_{2s+1})
      int s = p - 2048;
      u1 = 4096 + s; u2 = 2 * s + 1;
      a = shape + (size_t)s * KD;
      b = text + (size_t)(2 * s + 1) * KD;
    }
    float g1 = St[u1] + 2.0f * Ss[u1];
    float g2 = St[u2] + 2.0f * Ss[u2];
    base = g1 + g2 + ECONST;
    scale = 1.0f / 8192.0f;
  }
  float s = 0.f;
#pragma unroll
  for (int j = 0; j < 4; ++j) {
    int idx = j * 64 + lane;
    float d = a[idx] - b[idx];
    s += d * d;
  }
#pragma unroll
  for (int m = 1; m < 64; m <<= 1) s += __shfl_xor(s, m, 64);
  if (lane == 0) {
    float D = s > 0.f ? sqrtf(s) : 0.f;
    float ns = base - 2.0f * expf(1.0f - D);
    float J = logf(ns) + D;
    part[threadIdx.x >> 6] = (J > 0.f) ? J * J * scale : 0.f;
  }
  __syncthreads();
  if (threadIdx.x == 0)
    partials[blockIdx.x] = part[0] + part[1] + part[2] + part[3];
}

// ---- final: sum partials -> out[0] ----------------------------------------
__global__ __launch_bounds__(256) void reduce_kernel(const float* __restrict__ partials,
                                                     float* __restrict__ out, int out_n) {
  __shared__ float part[4];
  float s = 0.f;
  for (int i = threadIdx.x; i < LOSS_BLOCKS; i += 256) s += partials[i];
#pragma unroll
  for (int m = 1; m < 64; m <<= 1) s += __shfl_xor(s, m, 64);
  if ((threadIdx.x & 63) == 0) part[threadIdx.x >> 6] = s;
  __syncthreads();
  if (threadIdx.x == 0) out[0] = part[0] + part[1] + part[2] + part[3];
  else if (threadIdx.x < out_n) out[threadIdx.x] = 0.f;
}

extern "C" void kernel_launch(void* const* d_in, const int* in_sizes, int n_in,
                              void* d_out, int out_size, void* d_ws, size_t ws_size,
                              hipStream_t stream) {
  const float* text = (const float*)d_in[0];
  const float* shape = (const float*)d_in[1];
  float* out = (float*)d_out;

  char* ws = (char*)d_ws;
  __bf16* Xu = (__bf16*)ws;                        // 3 MB
  float* sq = (float*)(ws + (size_t)NU * KD * 2);  // 24 KB
  float* rowacc = sq + NU;                         // 48 KB (St ++ Ss)
  float* partials = rowacc + 2 * NU;               // 6 KB
  float* rowpart = partials + LOSS_BLOCKS;         // 588 KB
  float* colpart = rowpart + (size_t)TU * 128;     // 588 KB

  prep_kernel<<<NU / 4, 256, 0, stream>>>(text, shape, Xu, sq);
  egemm_tri_kernel<<<TU, 256, 0, stream>>>(Xu, sq, rowpart, colpart);
  rowreduce_kernel<<<NBU / 2, 256, 0, stream>>>(rowpart, colpart, rowacc);
  loss_kernel<<<LOSS_BLOCKS, 256, 0, stream>>>(text, shape, rowacc, partials);
  reduce_kernel<<<1, 256, 0, stream>>>(partials, out, out_size);
}